// Round 1
// baseline (116.365 us; speedup 1.0000x reference)
//
#include <hip/hip_runtime.h>

// Problem constants (from reference)
#define V 49688
#define D 128
#define B 16
#define N 100
#define VD (V * D)        // 6,360,064 floats per batch copy
#define VD4 (VD / 4)      // 1,590,016 float4 per batch copy  (= 6211 * 256 exactly)

typedef float f32x4 __attribute__((ext_vector_type(4)));

// Kernel 1: out[b] = W  for b in [0, B)
// grid = (VD4/256, B), block = 256. One float4 per thread, exact fit.
// Non-temporal stores: the 407 MB output stream is write-once, keep W in L2.
__global__ __launch_bounds__(256) void GlobalGatedUpdate_copy_kernel(
    const f32x4* __restrict__ W4, f32x4* __restrict__ out4) {
  int r = blockIdx.x * 256 + threadIdx.x;            // 0 .. VD4-1
  size_t o = (size_t)blockIdx.y * VD4 + (size_t)r;
  f32x4 v = W4[r];
  __builtin_nontemporal_store(v, &out4[o]);
}

// Kernel 2: for each (b, i): v = nodes[b*N+i];
//   out[b][v][:] = (1 - alpha[v]) * W[v][:] + alpha[v] * x[i][:]
// 32 float4 per row, 8 rows per 256-thread block, B*N = 1600 rows -> 200 blocks.
__global__ __launch_bounds__(256) void GlobalGatedUpdate_scatter_kernel(
    const int* __restrict__ nodes, const float* __restrict__ x,
    const float* __restrict__ W, const float* __restrict__ alpha,
    float* __restrict__ out) {
  int t = blockIdx.x * 256 + threadIdx.x;            // 0 .. B*N*32 - 1
  int d4  = t & 31;                                  // float4 index within row
  int row = t >> 5;                                  // 0 .. 1599 (= b*N + i)
  int b = row / N;
  int i = row - b * N;                               // position in node list -> x row
  int v = nodes[row];
  float a = alpha[v];                                // alpha is (V,1)
  f32x4 wv = ((const f32x4*)W)[v * 32 + d4];
  f32x4 xv = ((const f32x4*)x)[i * 32 + d4];
  f32x4 res = (1.0f - a) * wv + a * xv;
  ((f32x4*)out)[(size_t)b * (size_t)VD4 + (size_t)(v * 32 + d4)] = res;
}

extern "C" void kernel_launch(void* const* d_in, const int* in_sizes, int n_in,
                              void* d_out, int out_size, void* d_ws, size_t ws_size,
                              hipStream_t stream) {
  const int*   nodes = (const int*)d_in[0];   // (B, N) int32
  const float* x     = (const float*)d_in[1]; // (B*N, D) f32
  const float* W     = (const float*)d_in[2]; // (V, D) f32
  const float* alpha = (const float*)d_in[3]; // (V, 1) f32
  float* out = (float*)d_out;                 // (B, V, D) f32

  dim3 grid_copy(VD4 / 256, B);               // 6211 x 16 blocks
  GlobalGatedUpdate_copy_kernel<<<grid_copy, 256, 0, stream>>>(
      (const f32x4*)W, (f32x4*)out);

  GlobalGatedUpdate_scatter_kernel<<<(B * N * 32) / 256, 256, 0, stream>>>(
      nodes, x, W, alpha, out);
}

// Round 2
// 87.964 us; speedup vs baseline: 1.3229x; 1.3229x over previous
//
#include <hip/hip_runtime.h>

// Problem constants (from reference)
#define V 49688
#define D 128
#define B 16
#define N 100
#define VD (V * D)        // 6,360,064 floats per batch copy
#define VD4 (VD / 4)      // 1,590,016 float4 per batch copy  (= 6211 * 256 exactly)

typedef float f32x4 __attribute__((ext_vector_type(4)));

// Kernel 1: out[b] = W for all b — read W once, broadcast-store to 16 batches.
// grid = VD4/256 = 6211 blocks, block = 256. Each thread: 1 load, 16 NT stores.
// Non-temporal stores: the 407 MB output stream is write-once; don't evict W.
__global__ __launch_bounds__(256) void GlobalGatedUpdate_copy_kernel(
    const f32x4* __restrict__ W4, f32x4* __restrict__ out4) {
  int r = blockIdx.x * 256 + threadIdx.x;            // 0 .. VD4-1 (exact fit)
  f32x4 v = W4[r];
  f32x4* p = out4 + r;
  #pragma unroll
  for (int b = 0; b < B; ++b) {
    __builtin_nontemporal_store(v, p);
    p += VD4;
  }
}

// Kernel 2: for each (b, i): v = nodes[b*N+i];
//   out[b][v][:] = (1 - alpha[v]) * W[v][:] + alpha[v] * x[i][:]
// 32 float4 per row, 8 rows per 256-thread block, B*N = 1600 rows -> 200 blocks.
__global__ __launch_bounds__(256) void GlobalGatedUpdate_scatter_kernel(
    const int* __restrict__ nodes, const float* __restrict__ x,
    const float* __restrict__ W, const float* __restrict__ alpha,
    float* __restrict__ out) {
  int t = blockIdx.x * 256 + threadIdx.x;            // 0 .. B*N*32 - 1
  int d4  = t & 31;                                  // float4 index within row
  int row = t >> 5;                                  // 0 .. 1599 (= b*N + i)
  int b = row / N;
  int i = row - b * N;                               // position in node list -> x row
  int v = nodes[row];
  float a = alpha[v];                                // alpha is (V,1)
  f32x4 wv = ((const f32x4*)W)[v * 32 + d4];
  f32x4 xv = ((const f32x4*)x)[i * 32 + d4];
  f32x4 res = (1.0f - a) * wv + a * xv;
  ((f32x4*)out)[(size_t)b * (size_t)VD4 + (size_t)(v * 32 + d4)] = res;
}

extern "C" void kernel_launch(void* const* d_in, const int* in_sizes, int n_in,
                              void* d_out, int out_size, void* d_ws, size_t ws_size,
                              hipStream_t stream) {
  const int*   nodes = (const int*)d_in[0];   // (B, N) int32
  const float* x     = (const float*)d_in[1]; // (B*N, D) f32
  const float* W     = (const float*)d_in[2]; // (V, D) f32
  const float* alpha = (const float*)d_in[3]; // (V, 1) f32
  float* out = (float*)d_out;                 // (B, V, D) f32

  GlobalGatedUpdate_copy_kernel<<<VD4 / 256, 256, 0, stream>>>(
      (const f32x4*)W, (f32x4*)out);

  GlobalGatedUpdate_scatter_kernel<<<(B * N * 32) / 256, 256, 0, stream>>>(
      nodes, x, W, alpha, out);
}